// Round 8
// baseline (12.566 us; speedup 1.0000x reference)
//
#include <hip/hip_runtime.h>
#include <math.h>

// out[n,d] = (0.5 - (1/256) * sum_k |tanh(x[n,k]) - tanh(w[d,k])|) * gain[d]
// Straight-through estimator: forward value is the L1 branch only.
//
// Round-8: revert to round-6 geometry (32x32 tile, 256 thr, 512 blocks = 2/CU
// -- the constrained optimum of quant redundancy 134M*(1/BM+1/BN) s.t. >=2
// blocks/CU) + T14 staging split: issue ALL 16 global loads first (regs),
// then quant + LDS write, so HBM/L2 latency isn't serialized behind the
// trans-pipe quant math. Quant: e=exp2(2log2e*x); r=rcp(e+1);
// q=fma(-255,r,255.5); pack v_cvt_pk_u8_f32. Core: v_sad_u8 (4 |a-b|+acc/op),
// broadcast LDS reads, one barrier.

#define DIN 256
#define BM 32
#define BN 32
#define XSTR 272   // LDS row stride in bytes (256 + 16)

__device__ __forceinline__ unsigned sad_u8(unsigned a, unsigned b, unsigned acc) {
#if __has_builtin(__builtin_amdgcn_sad_u8)
  return __builtin_amdgcn_sad_u8(a, b, acc);
#else
  unsigned d;
  asm("v_sad_u8 %0, %1, %2, %3" : "=v"(d) : "v"(a), "v"(b), "v"(acc));
  return d;
#endif
}

__device__ __forceinline__ float rcp_f(float v) {
#if __has_builtin(__builtin_amdgcn_rcpf)
  return __builtin_amdgcn_rcpf(v);
#else
  return 1.0f / v;
#endif
}

// q = round_half_up(255 * (tanh(x)+1)/2), branch/clamp-free
__device__ __forceinline__ float quant1(float x) {
  float e = exp2f(x * 2.8853900817779268f);   // e^(2x) via v_exp_f32
  float r = rcp_f(e + 1.0f);                  // x->+inf: 0, x->-inf: 1
  return fmaf(-255.0f, r, 255.5f);            // in [0.5, 255.5]
}

__device__ __forceinline__ unsigned quant4(float4 v) {
  float q0 = quant1(v.x), q1 = quant1(v.y), q2 = quant1(v.z), q3 = quant1(v.w);
#if __has_builtin(__builtin_amdgcn_cvt_pk_u8_f32)
  unsigned p = 0;
  p = __builtin_amdgcn_cvt_pk_u8_f32(q0, 0, p);
  p = __builtin_amdgcn_cvt_pk_u8_f32(q1, 1, p);
  p = __builtin_amdgcn_cvt_pk_u8_f32(q2, 2, p);
  p = __builtin_amdgcn_cvt_pk_u8_f32(q3, 3, p);
  return p;
#else
  return (unsigned)q0 | ((unsigned)q1 << 8) | ((unsigned)q2 << 16) | ((unsigned)q3 << 24);
#endif
}

__global__ __launch_bounds__(256) void fused_sad_kernel(
    const float* __restrict__ X,   // (N, 256) f32
    const float* __restrict__ W,   // (256, 256) f32
    const float* __restrict__ G,   // (256,)
    float* __restrict__ out) {     // (N, 256) f32
  __shared__ __align__(16) unsigned char xs[BM * XSTR];   // 8.5 KB
  __shared__ __align__(16) unsigned char wsl[BN * XSTR];  // 8.5 KB

  const int tid = threadIdx.x;
  const int r0 = blockIdx.x * BM;
  const int c0 = blockIdx.y * BN;

  // ---- phase A: issue all 16 independent global loads (latency overlapped)
  const int row = tid >> 3;           // 0..31 (8 threads per row)
  const int cq  = (tid & 7) * 8;      // chunk base 0,8,..,56 (of 64 per row)
  const float* xrow = &X[(size_t)(r0 + row) * DIN + cq * 4];
  const float* wrow = &W[(size_t)(c0 + row) * DIN + cq * 4];
  float4 xv0 = reinterpret_cast<const float4*>(xrow)[0];
  float4 xv1 = reinterpret_cast<const float4*>(xrow)[1];
  float4 xv2 = reinterpret_cast<const float4*>(xrow)[2];
  float4 xv3 = reinterpret_cast<const float4*>(xrow)[3];
  float4 xv4 = reinterpret_cast<const float4*>(xrow)[4];
  float4 xv5 = reinterpret_cast<const float4*>(xrow)[5];
  float4 xv6 = reinterpret_cast<const float4*>(xrow)[6];
  float4 xv7 = reinterpret_cast<const float4*>(xrow)[7];
  float4 wv0 = reinterpret_cast<const float4*>(wrow)[0];
  float4 wv1 = reinterpret_cast<const float4*>(wrow)[1];
  float4 wv2 = reinterpret_cast<const float4*>(wrow)[2];
  float4 wv3 = reinterpret_cast<const float4*>(wrow)[3];
  float4 wv4 = reinterpret_cast<const float4*>(wrow)[4];
  float4 wv5 = reinterpret_cast<const float4*>(wrow)[5];
  float4 wv6 = reinterpret_cast<const float4*>(wrow)[6];
  float4 wv7 = reinterpret_cast<const float4*>(wrow)[7];

  // ---- phase B: quant + LDS write (contiguous 8 dwords per thread per tile)
  unsigned* xd = reinterpret_cast<unsigned*>(&xs[row * XSTR + cq * 4]);
  unsigned* wd = reinterpret_cast<unsigned*>(&wsl[row * XSTR + cq * 4]);
  xd[0] = quant4(xv0); xd[1] = quant4(xv1); xd[2] = quant4(xv2); xd[3] = quant4(xv3);
  xd[4] = quant4(xv4); xd[5] = quant4(xv5); xd[6] = quant4(xv6); xd[7] = quant4(xv7);
  wd[0] = quant4(wv0); wd[1] = quant4(wv1); wd[2] = quant4(wv2); wd[3] = quant4(wv3);
  wd[4] = quant4(wv4); wd[5] = quant4(wv5); wd[6] = quant4(wv6); wd[7] = quant4(wv7);
  __syncthreads();

  const int wave = tid >> 6;            // 2x2 wave grid of 16x16 sub-tiles
  const int wr = (wave >> 1) * 16;
  const int wc = (wave & 1) * 16;
  const int lane = tid & 63;
  const int tr = lane >> 3;             // 0..7  (x-rows tr, tr+8)
  const int tc = lane & 7;              // 0..7  (w-cols 2tc, 2tc+1)

  const unsigned char* xr0 = &xs[(wr + tr) * XSTR];
  const unsigned char* xr1 = xr0 + 8 * XSTR;
  const unsigned char* wc0 = &wsl[(wc + 2 * tc) * XSTR];
  const unsigned char* wc1 = wc0 + XSTR;

  unsigned a00 = 0, a01 = 0, a10 = 0, a11 = 0;
#pragma unroll
  for (int k = 0; k < 16; ++k) {
    uint4 xa = *reinterpret_cast<const uint4*>(xr0 + k * 16);
    uint4 xb = *reinterpret_cast<const uint4*>(xr1 + k * 16);
    uint4 wa = *reinterpret_cast<const uint4*>(wc0 + k * 16);
    uint4 wb = *reinterpret_cast<const uint4*>(wc1 + k * 16);
    a00 = sad_u8(xa.x, wa.x, a00); a01 = sad_u8(xa.x, wb.x, a01);
    a10 = sad_u8(xb.x, wa.x, a10); a11 = sad_u8(xb.x, wb.x, a11);
    a00 = sad_u8(xa.y, wa.y, a00); a01 = sad_u8(xa.y, wb.y, a01);
    a10 = sad_u8(xb.y, wa.y, a10); a11 = sad_u8(xb.y, wb.y, a11);
    a00 = sad_u8(xa.z, wa.z, a00); a01 = sad_u8(xa.z, wb.z, a01);
    a10 = sad_u8(xb.z, wa.z, a10); a11 = sad_u8(xb.z, wb.z, a11);
    a00 = sad_u8(xa.w, wa.w, a00); a01 = sad_u8(xa.w, wb.w, a01);
    a10 = sad_u8(xb.w, wa.w, a10); a11 = sad_u8(xb.w, wb.w, a11);
  }

  const float s = 1.0f / (127.5f * 256.0f);
  const int R0 = r0 + wr + tr;
  const int R1 = R0 + 8;
  const int C0 = c0 + wc + 2 * tc;
  const float g0 = G[C0], g1 = G[C0 + 1];
  float2 o0, o1;
  o0.x = (0.5f - a00 * s) * g0; o0.y = (0.5f - a01 * s) * g1;
  o1.x = (0.5f - a10 * s) * g0; o1.y = (0.5f - a11 * s) * g1;
  *reinterpret_cast<float2*>(&out[(size_t)R0 * 256 + C0]) = o0;
  *reinterpret_cast<float2*>(&out[(size_t)R1 * 256 + C0]) = o1;
}

// ---------------- fallback (shape misfit): fused f32 path ----------------
#define KT 128
#define STRIDE 132
#define TM 32
#define TN 32

__device__ __forceinline__ float4 tanh4(float4 v) {
  v.x = tanhf(v.x); v.y = tanhf(v.y); v.z = tanhf(v.z); v.w = tanhf(v.w);
  return v;
}

__global__ __launch_bounds__(256, 2) void l1_f32_fused_kernel(
    const float* __restrict__ X, const float* __restrict__ W,
    const float* __restrict__ G, float* __restrict__ out) {
  __shared__ float xs[TM * STRIDE];
  __shared__ float wsl[TN * STRIDE];
  const int tid = threadIdx.x;
  const int r0 = blockIdx.x * TM;
  const int c0 = blockIdx.y * TN;
  const int wave = tid >> 6;
  const int lane = tid & 63;
  const int lr = lane >> 4;
  const int lc = lane & 15;
  float acc[2][2] = {{0.f, 0.f}, {0.f, 0.f}};
  for (int kp = 0; kp < DIN; kp += KT) {
    __syncthreads();
    for (int it = tid; it < TM * (KT / 4); it += 256) {
      int r = it >> 5, c4 = it & 31;
      float4 v = *reinterpret_cast<const float4*>(X + (size_t)(r0 + r) * DIN + kp + c4 * 4);
      *reinterpret_cast<float4*>(&xs[r * STRIDE + c4 * 4]) = tanh4(v);
    }
    for (int it = tid; it < TN * (KT / 4); it += 256) {
      int r = it >> 5, c4 = it & 31;
      float4 v = *reinterpret_cast<const float4*>(W + (size_t)(c0 + r) * DIN + kp + c4 * 4);
      *reinterpret_cast<float4*>(&wsl[r * STRIDE + c4 * 4]) = tanh4(v);
    }
    __syncthreads();
    const float* xb = &xs[(8 * wave + lr) * STRIDE];
    const float* wb = &wsl[lc * STRIDE];
#pragma unroll
    for (int k = 0; k < KT; k += 4) {
      float4 x0 = *reinterpret_cast<const float4*>(xb + k);
      float4 x1 = *reinterpret_cast<const float4*>(xb + 4 * STRIDE + k);
      float4 w0 = *reinterpret_cast<const float4*>(wb + k);
      float4 w1 = *reinterpret_cast<const float4*>(wb + 16 * STRIDE + k);
      acc[0][0] += (fabsf(x0.x - w0.x) + fabsf(x0.y - w0.y)) + (fabsf(x0.z - w0.z) + fabsf(x0.w - w0.w));
      acc[0][1] += (fabsf(x0.x - w1.x) + fabsf(x0.y - w1.y)) + (fabsf(x0.z - w1.z) + fabsf(x0.w - w1.w));
      acc[1][0] += (fabsf(x1.x - w0.x) + fabsf(x1.y - w0.y)) + (fabsf(x1.z - w0.z) + fabsf(x1.w - w0.w));
      acc[1][1] += (fabsf(x1.x - w1.x) + fabsf(x1.y - w1.y)) + (fabsf(x1.z - w1.z) + fabsf(x1.w - w1.w));
    }
  }
  const float inv = 1.0f / DIN;
#pragma unroll
  for (int j = 0; j < 2; ++j) {
    int C = c0 + lc + 16 * j;
    float g = G[C];
#pragma unroll
    for (int i = 0; i < 2; ++i) {
      int R = r0 + 8 * wave + lr + 4 * i;
      out[(size_t)R * 256 + C] = (0.5f - acc[i][j] * inv) * g;
    }
  }
}

extern "C" void kernel_launch(void* const* d_in, const int* in_sizes, int n_in,
                              void* d_out, int out_size, void* d_ws, size_t ws_size,
                              hipStream_t stream) {
  const float* x = (const float*)d_in[0];   // (2,1024,256) f32
  const float* w = (const float*)d_in[1];   // (256,256) f32
  const float* g = (const float*)d_in[2];   // (1,256,1) f32
  float* out = (float*)d_out;

  const int N = in_sizes[0] / DIN;          // 2048
  const int Dout = 256;

  if ((N % BM) == 0) {
    dim3 grid(N / BM, Dout / BN);           // (64, 8) = 512 blocks, 2/CU
    fused_sad_kernel<<<grid, 256, 0, stream>>>(x, w, g, out);
  } else {
    dim3 grid((N + TM - 1) / TM, Dout / TN);
    l1_f32_fused_kernel<<<grid, 256, 0, stream>>>(x, w, g, out);
  }
}

// Round 9
// 11.069 us; speedup vs baseline: 1.1353x; 1.1353x over previous
//
#include <hip/hip_runtime.h>
#include <math.h>

// out[n,d] = (0.5 - (1/256) * sum_k |tanh(x[n,k]) - tanh(w[d,k])|) * gain[d]
// Straight-through estimator: forward value is the L1 branch only.
//
// FINAL (= round-6 best, 10.99us): single fused kernel. 32x32 output tile,
// 256 threads, 512 blocks (2/CU) -- constrained optimum of quant redundancy
// 134M*(1/BM+1/BN) s.t. >=2 blocks/CU for staging/SAD cross-block overlap.
// Each block tanh-quantizes its x/w tiles to u8 in LDS with coalesced
// interleaved staging (consecutive lanes -> consecutive 16B chunks), then
// the L1 core is v_sad_u8 (4 |a-b| + accumulate per VALU op) on 8-way
// broadcast LDS reads. Quant: e=exp2(2log2e*x); r=rcp(e+1);
// q=fma(-255,r,255.5); pack via v_cvt_pk_u8_f32. One barrier, no workspace.
// dur_us ~11 is dominated by a ~9-10us graph-replay/launch floor; in-kernel
// work ~1-2us (R7/R8 experiments: tile reshape and staging split both
// regressed -- geometry and scheduling levers are exhausted at this size).

#define DIN 256
#define BM 32
#define BN 32
#define XSTR 272   // LDS row stride in bytes (256 + 16)

__device__ __forceinline__ unsigned sad_u8(unsigned a, unsigned b, unsigned acc) {
#if __has_builtin(__builtin_amdgcn_sad_u8)
  return __builtin_amdgcn_sad_u8(a, b, acc);
#else
  unsigned d;
  asm("v_sad_u8 %0, %1, %2, %3" : "=v"(d) : "v"(a), "v"(b), "v"(acc));
  return d;
#endif
}

__device__ __forceinline__ float rcp_f(float v) {
#if __has_builtin(__builtin_amdgcn_rcpf)
  return __builtin_amdgcn_rcpf(v);
#else
  return 1.0f / v;
#endif
}

// q = round_half_up(255 * (tanh(x)+1)/2), branch/clamp-free
__device__ __forceinline__ float quant1(float x) {
  float e = exp2f(x * 2.8853900817779268f);   // e^(2x) via v_exp_f32
  float r = rcp_f(e + 1.0f);                  // x->+inf: 0, x->-inf: 1
  return fmaf(-255.0f, r, 255.5f);            // in [0.5, 255.5]
}

__device__ __forceinline__ unsigned quant4(float4 v) {
  float q0 = quant1(v.x), q1 = quant1(v.y), q2 = quant1(v.z), q3 = quant1(v.w);
#if __has_builtin(__builtin_amdgcn_cvt_pk_u8_f32)
  unsigned p = 0;
  p = __builtin_amdgcn_cvt_pk_u8_f32(q0, 0, p);
  p = __builtin_amdgcn_cvt_pk_u8_f32(q1, 1, p);
  p = __builtin_amdgcn_cvt_pk_u8_f32(q2, 2, p);
  p = __builtin_amdgcn_cvt_pk_u8_f32(q3, 3, p);
  return p;
#else
  return (unsigned)q0 | ((unsigned)q1 << 8) | ((unsigned)q2 << 16) | ((unsigned)q3 << 24);
#endif
}

__global__ __launch_bounds__(256) void fused_sad_kernel(
    const float* __restrict__ X,   // (N, 256) f32
    const float* __restrict__ W,   // (256, 256) f32
    const float* __restrict__ G,   // (256,)
    float* __restrict__ out) {     // (N, 256) f32
  __shared__ __align__(16) unsigned char xs[BM * XSTR];   // 8.5 KB
  __shared__ __align__(16) unsigned char wsl[BN * XSTR];  // 8.5 KB

  const int tid = threadIdx.x;
  const int r0 = blockIdx.x * BM;
  const int c0 = blockIdx.y * BN;

  // stage + tanh + quantize both tiles: 32 rows x 64 float4-chunks each.
  // consecutive tids hit consecutive 16B global chunks (coalesced) and
  // consecutive LDS dwords (bank-cycling, conflict-free).
#pragma unroll
  for (int p = 0; p < 8; ++p) {
    int id  = tid + p * 256;        // 0..2047
    int row = id >> 6;
    int c4  = id & 63;
    float4 xv = *reinterpret_cast<const float4*>(&X[(size_t)(r0 + row) * DIN + c4 * 4]);
    *reinterpret_cast<unsigned*>(&xs[row * XSTR + c4 * 4]) = quant4(xv);
    float4 wv = *reinterpret_cast<const float4*>(&W[(size_t)(c0 + row) * DIN + c4 * 4]);
    *reinterpret_cast<unsigned*>(&wsl[row * XSTR + c4 * 4]) = quant4(wv);
  }
  __syncthreads();

  const int wave = tid >> 6;            // 2x2 wave grid of 16x16 sub-tiles
  const int wr = (wave >> 1) * 16;
  const int wc = (wave & 1) * 16;
  const int lane = tid & 63;
  const int tr = lane >> 3;             // 0..7  (x-rows tr, tr+8)
  const int tc = lane & 7;              // 0..7  (w-cols 2tc, 2tc+1)

  const unsigned char* xr0 = &xs[(wr + tr) * XSTR];
  const unsigned char* xr1 = xr0 + 8 * XSTR;
  const unsigned char* wc0 = &wsl[(wc + 2 * tc) * XSTR];
  const unsigned char* wc1 = wc0 + XSTR;

  unsigned a00 = 0, a01 = 0, a10 = 0, a11 = 0;
#pragma unroll
  for (int k = 0; k < 16; ++k) {
    uint4 xv0 = *reinterpret_cast<const uint4*>(xr0 + k * 16);
    uint4 xv1 = *reinterpret_cast<const uint4*>(xr1 + k * 16);
    uint4 wv0 = *reinterpret_cast<const uint4*>(wc0 + k * 16);
    uint4 wv1 = *reinterpret_cast<const uint4*>(wc1 + k * 16);
    a00 = sad_u8(xv0.x, wv0.x, a00); a01 = sad_u8(xv0.x, wv1.x, a01);
    a10 = sad_u8(xv1.x, wv0.x, a10); a11 = sad_u8(xv1.x, wv1.x, a11);
    a00 = sad_u8(xv0.y, wv0.y, a00); a01 = sad_u8(xv0.y, wv1.y, a01);
    a10 = sad_u8(xv1.y, wv0.y, a10); a11 = sad_u8(xv1.y, wv1.y, a11);
    a00 = sad_u8(xv0.z, wv0.z, a00); a01 = sad_u8(xv0.z, wv1.z, a01);
    a10 = sad_u8(xv1.z, wv0.z, a10); a11 = sad_u8(xv1.z, wv1.z, a11);
    a00 = sad_u8(xv0.w, wv0.w, a00); a01 = sad_u8(xv0.w, wv1.w, a01);
    a10 = sad_u8(xv1.w, wv0.w, a10); a11 = sad_u8(xv1.w, wv1.w, a11);
  }

  const float s = 1.0f / (127.5f * 256.0f);
  const int R0 = r0 + wr + tr;
  const int R1 = R0 + 8;
  const int C0 = c0 + wc + 2 * tc;
  const float g0 = G[C0], g1 = G[C0 + 1];
  float2 o0, o1;
  o0.x = (0.5f - a00 * s) * g0; o0.y = (0.5f - a01 * s) * g1;
  o1.x = (0.5f - a10 * s) * g0; o1.y = (0.5f - a11 * s) * g1;
  *reinterpret_cast<float2*>(&out[(size_t)R0 * 256 + C0]) = o0;
  *reinterpret_cast<float2*>(&out[(size_t)R1 * 256 + C0]) = o1;
}

// ---------------- fallback (shape misfit): fused f32 path ----------------
#define KT 128
#define STRIDE 132
#define TM 32
#define TN 32

__device__ __forceinline__ float4 tanh4(float4 v) {
  v.x = tanhf(v.x); v.y = tanhf(v.y); v.z = tanhf(v.z); v.w = tanhf(v.w);
  return v;
}

__global__ __launch_bounds__(256, 2) void l1_f32_fused_kernel(
    const float* __restrict__ X, const float* __restrict__ W,
    const float* __restrict__ G, float* __restrict__ out) {
  __shared__ float xs[TM * STRIDE];
  __shared__ float wsl[TN * STRIDE];
  const int tid = threadIdx.x;
  const int r0 = blockIdx.x * TM;
  const int c0 = blockIdx.y * TN;
  const int wave = tid >> 6;
  const int lane = tid & 63;
  const int lr = lane >> 4;
  const int lc = lane & 15;
  float acc[2][2] = {{0.f, 0.f}, {0.f, 0.f}};
  for (int kp = 0; kp < DIN; kp += KT) {
    __syncthreads();
    for (int it = tid; it < TM * (KT / 4); it += 256) {
      int r = it >> 5, c4 = it & 31;
      float4 v = *reinterpret_cast<const float4*>(X + (size_t)(r0 + r) * DIN + kp + c4 * 4);
      *reinterpret_cast<float4*>(&xs[r * STRIDE + c4 * 4]) = tanh4(v);
    }
    for (int it = tid; it < TN * (KT / 4); it += 256) {
      int r = it >> 5, c4 = it & 31;
      float4 v = *reinterpret_cast<const float4*>(W + (size_t)(c0 + r) * DIN + kp + c4 * 4);
      *reinterpret_cast<float4*>(&wsl[r * STRIDE + c4 * 4]) = tanh4(v);
    }
    __syncthreads();
    const float* xb = &xs[(8 * wave + lr) * STRIDE];
    const float* wb = &wsl[lc * STRIDE];
#pragma unroll
    for (int k = 0; k < KT; k += 4) {
      float4 x0 = *reinterpret_cast<const float4*>(xb + k);
      float4 x1 = *reinterpret_cast<const float4*>(xb + 4 * STRIDE + k);
      float4 w0 = *reinterpret_cast<const float4*>(wb + k);
      float4 w1 = *reinterpret_cast<const float4*>(wb + 16 * STRIDE + k);
      acc[0][0] += (fabsf(x0.x - w0.x) + fabsf(x0.y - w0.y)) + (fabsf(x0.z - w0.z) + fabsf(x0.w - w0.w));
      acc[0][1] += (fabsf(x0.x - w1.x) + fabsf(x0.y - w1.y)) + (fabsf(x0.z - w1.z) + fabsf(x0.w - w1.w));
      acc[1][0] += (fabsf(x1.x - w0.x) + fabsf(x1.y - w0.y)) + (fabsf(x1.z - w0.z) + fabsf(x1.w - w0.w));
      acc[1][1] += (fabsf(x1.x - w1.x) + fabsf(x1.y - w1.y)) + (fabsf(x1.z - w1.z) + fabsf(x1.w - w1.w));
    }
  }
  const float inv = 1.0f / DIN;
#pragma unroll
  for (int j = 0; j < 2; ++j) {
    int C = c0 + lc + 16 * j;
    float g = G[C];
#pragma unroll
    for (int i = 0; i < 2; ++i) {
      int R = r0 + 8 * wave + lr + 4 * i;
      out[(size_t)R * 256 + C] = (0.5f - acc[i][j] * inv) * g;
    }
  }
}

extern "C" void kernel_launch(void* const* d_in, const int* in_sizes, int n_in,
                              void* d_out, int out_size, void* d_ws, size_t ws_size,
                              hipStream_t stream) {
  const float* x = (const float*)d_in[0];   // (2,1024,256) f32
  const float* w = (const float*)d_in[1];   // (256,256) f32
  const float* g = (const float*)d_in[2];   // (1,256,1) f32
  float* out = (float*)d_out;

  const int N = in_sizes[0] / DIN;          // 2048
  const int Dout = 256;

  if ((N % BM) == 0) {
    dim3 grid(N / BM, Dout / BN);           // (64, 8) = 512 blocks, 2/CU
    fused_sad_kernel<<<grid, 256, 0, stream>>>(x, w, g, out);
  } else {
    dim3 grid((N + TM - 1) / TM, Dout / TN);
    l1_f32_fused_kernel<<<grid, 256, 0, stream>>>(x, w, g, out);
  }
}